// Round 1
// baseline (424.008 us; speedup 1.0000x reference)
//
#include <hip/hip_runtime.h>
#include <math.h>

#define NEG_SLOPE 0.01f

// ---------------------------------------------------------------------------
// Kernel 1: per-node precompute.
//   sl[n]  = v[n] . (attl @ Wa)      (scalar)
//   sr[n]  = v[n] . (attr @ Wa)      (scalar)
//   vg0[n] = v[n] . gl               (scalar)
//   vr[n]  = v[n] . gr               (scalar)
//   gp[n]  = Wg @ v[n]               (64-dim, needed for per-dim segment max)
// One wave (64 lanes) per node, lane = dim.
// ---------------------------------------------------------------------------
__global__ __launch_bounds__(256) void node_pre(
    const float* __restrict__ v, const float* __restrict__ Wa,
    const float* __restrict__ attl, const float* __restrict__ attr,
    const float* __restrict__ Wg, const float* __restrict__ gl,
    const float* __restrict__ gr,
    float* __restrict__ sl, float* __restrict__ sr,
    float* __restrict__ vg0, float* __restrict__ vr,
    float* __restrict__ gp, int N)
{
    __shared__ float wgT[64 * 64];   // Wg transposed: wgT[k*64+d] = Wg[d*64+k]
    int tid = threadIdx.x;
    for (int t = tid; t < 64 * 64; t += 256) {
        int r = t >> 6, c = t & 63;
        wgT[c * 64 + r] = Wg[t];
    }
    __syncthreads();

    int n = blockIdx.x * 4 + (tid >> 6);
    int d = tid & 63;
    if (n >= N) return;

    float vd = v[(size_t)n * 64 + d];

    // al[d] = sum_k attl[k]*Wa[k][d]  (Wa row reads are lane-coalesced)
    float al_d = 0.f, ar_d = 0.f;
    #pragma unroll
    for (int k = 0; k < 64; ++k) {
        float wa = Wa[k * 64 + d];
        al_d = fmaf(attl[k], wa, al_d);
        ar_d = fmaf(attr[k], wa, ar_d);
    }

    float p1 = al_d * vd, p2 = ar_d * vd, p3 = gl[d] * vd, p4 = gr[d] * vd;
    #pragma unroll
    for (int o = 32; o > 0; o >>= 1) {
        p1 += __shfl_xor(p1, o);
        p2 += __shfl_xor(p2, o);
        p3 += __shfl_xor(p3, o);
        p4 += __shfl_xor(p4, o);
    }
    if (d == 0) { sl[n] = p1; sr[n] = p2; vg0[n] = p3; vr[n] = p4; }

    // gp[n][d] = sum_k Wg[d][k] * v[n][k]; Wg from LDS (transposed, conflict-free),
    // v broadcast via shuffle.
    float acc = 0.f;
    #pragma unroll
    for (int k = 0; k < 64; ++k) {
        float vk = __shfl(vd, k);
        acc = fmaf(wgT[k * 64 + d], vk, acc);
    }
    gp[(size_t)n * 64 + d] = acc;
}

// ---------------------------------------------------------------------------
// CSR build: degree count -> exclusive scan -> scatter edge ids grouped by dst
// ---------------------------------------------------------------------------
__global__ __launch_bounds__(256) void deg_count(const int* __restrict__ dst,
                                                 int* __restrict__ deg, int E)
{
    int e = blockIdx.x * 256 + threadIdx.x;
    if (e < E) atomicAdd(&deg[dst[e]], 1);
}

__global__ __launch_bounds__(256) void scan_block(const int* __restrict__ deg,
                                                  int* __restrict__ offs,
                                                  int* __restrict__ bsum, int N)
{
    __shared__ int tmp[256];
    int t = threadIdx.x;
    int i = blockIdx.x * 256 + t;
    int val = (i < N) ? deg[i] : 0;
    tmp[t] = val;
    __syncthreads();
    #pragma unroll
    for (int o = 1; o < 256; o <<= 1) {
        int x = (t >= o) ? tmp[t - o] : 0;
        __syncthreads();
        tmp[t] += x;
        __syncthreads();
    }
    if (i < N) offs[i] = tmp[t] - val;            // exclusive within block
    if (t == 255) bsum[blockIdx.x] = tmp[255];    // block total
}

__global__ __launch_bounds__(256) void scan_top(int* __restrict__ bsum)
{
    __shared__ int tmp[256];
    int t = threadIdx.x;
    int val = bsum[t];
    tmp[t] = val;
    __syncthreads();
    #pragma unroll
    for (int o = 1; o < 256; o <<= 1) {
        int x = (t >= o) ? tmp[t - o] : 0;
        __syncthreads();
        tmp[t] += x;
        __syncthreads();
    }
    bsum[t] = tmp[t] - val;                       // exclusive block offsets
}

__global__ __launch_bounds__(256) void scan_add(int* __restrict__ offs,
                                                const int* __restrict__ bsum, int N)
{
    int i = blockIdx.x * 256 + threadIdx.x;
    if (i < N) offs[i] += bsum[blockIdx.x];
}

__global__ __launch_bounds__(256) void scatter_k(const int* __restrict__ dst,
                                                 const int* __restrict__ offs,
                                                 int* __restrict__ cursor,
                                                 int* __restrict__ csr, int E)
{
    int e = blockIdx.x * 256 + threadIdx.x;
    if (e < E) {
        int d = dst[e];
        int p = atomicAdd(&cursor[d], 1);
        csr[offs[d] + p] = e;
    }
}

// ---------------------------------------------------------------------------
// Main kernel: one wave per dst node. lane = output dim.
// Edge scalars computed lane-parallel (64 edges at a time), broadcast via shfl
// for the dim-parallel accumulation of h, per-dim max_feat, and softmax stats.
// ---------------------------------------------------------------------------
__global__ __launch_bounds__(256) void main_k(
    const float* __restrict__ proj_z, const float* __restrict__ pre_w,
    const int* __restrict__ src,
    const float* __restrict__ sl, const float* __restrict__ sr,
    const float* __restrict__ vg0, const float* __restrict__ vr,
    const float* __restrict__ gp, const float* __restrict__ gm,
    const int* __restrict__ deg, const int* __restrict__ offs,
    const int* __restrict__ csr,
    float* __restrict__ out, int N)
{
    int n = (blockIdx.x * blockDim.x + threadIdx.x) >> 6;
    int lane = threadIdx.x & 63;
    if (n >= N) return;

    int dg = deg[n];
    int st = offs[n];
    float srn = sr[n];

    float m = -INFINITY;      // running softmax max
    float den = 0.f;          // running softmax denominator
    float hacc = 0.f;         // running sum of ex * proj_z[src][lane]
    float mf = -INFINITY;     // per-dim running max of pre_w * gp[src][lane]
    float msum = 0.f;         // running sum of pre_w * (v[src].gr)

    for (int base = 0; base < dg; base += 64) {
        int cnt = min(64, dg - base);

        // lane-parallel: one edge per lane
        float lr = -INFINITY; int s_e = 0; float pw = 0.f;
        if (lane < cnt) {
            int e = csr[st + base + lane];
            s_e = src[e];
            pw = pre_w[e];
            float a = fmaf(pw, sl[s_e], srn);
            lr = (a >= 0.f) ? a : NEG_SLOPE * a;
        }

        // chunk max + online rescale
        float cm = lr;
        #pragma unroll
        for (int o = 32; o > 0; o >>= 1) cm = fmaxf(cm, __shfl_xor(cm, o));
        float mnew = fmaxf(m, cm);
        if (mnew > m) {
            float sc = __expf(m - mnew);   // m=-inf -> 0: zeroes empty acc, OK
            den *= sc;
            hacc *= sc;
            m = mnew;
        }

        // dim-parallel: iterate chunk edges serially, broadcast scalars
        for (int j = 0; j < cnt; ++j) {
            int   sj  = __shfl(s_e, j);
            float pwj = __shfl(pw, j);
            float lrj = __shfl(lr, j);
            float ex  = __expf(lrj - m);
            den += ex;
            hacc = fmaf(ex, proj_z[(size_t)sj * 64 + lane], hacc);
            mf   = fmaxf(mf, pwj * gp[(size_t)sj * 64 + lane]);
            msum = fmaf(pwj, vr[sj], msum);
        }
    }

    // gate
    float mfv = (dg > 0) ? mf : 0.f;           // masked segment_max
    float gdot = gm[lane] * mfv;
    #pragma unroll
    for (int o = 32; o > 0; o >>= 1) gdot += __shfl_xor(gdot, o);
    float mean = msum / fmaxf((float)dg, 1.f);
    float x = vg0[n] + gdot + mean;
    float gv = 1.f / (1.f + __expf(-x));

    float pz = proj_z[(size_t)n * 64 + lane];
    float res = pz + ((dg > 0) ? gv * hacc / den : 0.f);
    out[(size_t)n * 64 + lane] = res;
}

// ---------------------------------------------------------------------------
extern "C" void kernel_launch(void* const* d_in, const int* in_sizes, int n_in,
                              void* d_out, int out_size, void* d_ws, size_t ws_size,
                              hipStream_t stream)
{
    const float* v      = (const float*)d_in[0];
    const float* proj_z = (const float*)d_in[1];
    const float* pre_w  = (const float*)d_in[2];
    const float* Wa_w   = (const float*)d_in[3];
    const float* attl_w = (const float*)d_in[4];
    const float* attr_w = (const float*)d_in[5];
    const float* Wg_w   = (const float*)d_in[6];
    const float* gl_w   = (const float*)d_in[7];
    const float* gm_w   = (const float*)d_in[8];
    const float* gr_w   = (const float*)d_in[9];
    const int*   src    = (const int*)d_in[10];
    const int*   dst    = (const int*)d_in[11];

    const int N = in_sizes[0] / 64;
    const int E = in_sizes[10];
    float* out = (float*)d_out;

    // workspace carve-up (all 4B-aligned)
    char* ws = (char*)d_ws;
    float* sl     = (float*)ws; ws += (size_t)N * 4;
    float* sr     = (float*)ws; ws += (size_t)N * 4;
    float* vg0    = (float*)ws; ws += (size_t)N * 4;
    float* vr     = (float*)ws; ws += (size_t)N * 4;
    float* gp     = (float*)ws; ws += (size_t)N * 64 * 4;
    int*   deg    = (int*)ws;   ws += (size_t)N * 4;
    int*   offs   = (int*)ws;   ws += (size_t)N * 4;
    int*   cursor = (int*)ws;   ws += (size_t)N * 4;
    int*   bsum   = (int*)ws;   ws += 256 * 4;
    int*   csr    = (int*)ws;   ws += (size_t)E * 4;

    hipMemsetAsync(deg, 0, (size_t)N * 4, stream);
    hipMemsetAsync(cursor, 0, (size_t)N * 4, stream);

    node_pre<<<(N + 3) / 4, 256, 0, stream>>>(v, Wa_w, attl_w, attr_w, Wg_w,
                                              gl_w, gr_w, sl, sr, vg0, vr, gp, N);
    deg_count<<<(E + 255) / 256, 256, 0, stream>>>(dst, deg, E);

    int nScanBlocks = (N + 255) / 256;   // 256 for N=65536
    scan_block<<<nScanBlocks, 256, 0, stream>>>(deg, offs, bsum, N);
    scan_top<<<1, 256, 0, stream>>>(bsum);
    scan_add<<<nScanBlocks, 256, 0, stream>>>(offs, bsum, N);

    scatter_k<<<(E + 255) / 256, 256, 0, stream>>>(dst, offs, cursor, csr, E);

    main_k<<<(N + 3) / 4, 256, 0, stream>>>(proj_z, pre_w, src, sl, sr, vg0, vr,
                                            gp, gm_w, deg, offs, csr, out, N);
}

// Round 2
// 254.421 us; speedup vs baseline: 1.6666x; 1.6666x over previous
//
#include <hip/hip_runtime.h>
#include <math.h>

#define NEG_SLOPE 0.01f

// ---------------------------------------------------------------------------
// node_pre: per-node precompute, one 64-node tile per block.
//   sl[n]  = v[n] . (attl @ Wa)   sr[n] = v[n] . (attr @ Wa)
//   vg0[n] = v[n] . gl            vr[n] = v[n] . gr
//   gp[n]  = Wg @ v[n]            (64-dim)
// Wave per 16 nodes, lane = dim. Wg rows live in registers (lane d = row d).
// v tile staged in LDS stride-68 (conflict-free); gp inner loop reads the
// tile via uniform-address float4 broadcasts (free, no conflicts).
// ---------------------------------------------------------------------------
__global__ __launch_bounds__(256) void node_pre(
    const float* __restrict__ v, const float* __restrict__ Wa,
    const float* __restrict__ attl, const float* __restrict__ attr,
    const float* __restrict__ Wg, const float* __restrict__ gl,
    const float* __restrict__ gr,
    float* __restrict__ sl, float* __restrict__ sr,
    float* __restrict__ vg0, float* __restrict__ vr,
    float* __restrict__ gp, int N)
{
    __shared__ float vtile[64 * 68];   // stride 68: odd/4-aligned, conflict-free
    int t = threadIdx.x;
    int lane = t & 63;
    int w = t >> 6;

    // lane d holds Wg row d (contiguous 256B, L1/L2-cached, once per block)
    float wcol[64];
    #pragma unroll
    for (int k4 = 0; k4 < 64; k4 += 4) {
        float4 q = *(const float4*)(Wg + lane * 64 + k4);
        wcol[k4] = q.x; wcol[k4 + 1] = q.y; wcol[k4 + 2] = q.z; wcol[k4 + 3] = q.w;
    }

    // al/ar once per wave (not per node): al[d] = sum_k attl[k]*Wa[k][d]
    float ald = 0.f, ard = 0.f;
    #pragma unroll 8
    for (int k = 0; k < 64; ++k) {
        float wa = Wa[k * 64 + lane];          // coalesced row read
        ald = fmaf(attl[k], wa, ald);
        ard = fmaf(attr[k], wa, ard);
    }
    float gld = gl[lane], grd = gr[lane];

    for (int tile = blockIdx.x; (size_t)tile * 64 < (size_t)N; tile += gridDim.x) {
        int base = tile * 64;
        __syncthreads();                        // protect vtile from prev iter
        // stage 64x64 v tile: thread t loads 16 consecutive floats (coalesced)
        #pragma unroll
        for (int i = 0; i < 4; ++i) {
            int el = t * 16 + i * 4;            // element in tile, 0..4095
            size_t gidx = (size_t)base * 64 + el;
            if (gidx + 3 < (size_t)N * 64) {
                float4 q = *(const float4*)(v + gidx);
                int r = el >> 6, c = el & 63;
                *(float4*)&vtile[r * 68 + c] = q;
            }
        }
        __syncthreads();

        #pragma unroll 4
        for (int n = 0; n < 16; ++n) {
            int ln = w * 16 + n;
            int node = base + ln;
            if (node >= N) break;
            float vd = vtile[ln * 68 + lane];   // stride-1 per lane, 2-way free

            float p1 = ald * vd, p2 = ard * vd, p3 = gld * vd, p4 = grd * vd;
            #pragma unroll
            for (int o = 32; o > 0; o >>= 1) {
                p1 += __shfl_xor(p1, o);
                p2 += __shfl_xor(p2, o);
                p3 += __shfl_xor(p3, o);
                p4 += __shfl_xor(p4, o);
            }
            if (lane == 0) { sl[node] = p1; sr[node] = p2; vg0[node] = p3; vr[node] = p4; }

            // gp[node][d] = sum_k Wg[d][k]*v[node][k]; v via uniform broadcasts
            float acc = 0.f;
            #pragma unroll
            for (int k = 0; k < 64; k += 4) {
                float4 q = *(const float4*)&vtile[ln * 68 + k];  // uniform addr
                acc = fmaf(wcol[k], q.x, acc);
                acc = fmaf(wcol[k + 1], q.y, acc);
                acc = fmaf(wcol[k + 2], q.z, acc);
                acc = fmaf(wcol[k + 3], q.w, acc);
            }
            gp[(size_t)node * 64 + lane] = acc;
        }
    }
}

// ---------------------------------------------------------------------------
// CSR build: degree count -> exclusive scan -> scatter (src, pre_w) by dst
// ---------------------------------------------------------------------------
__global__ __launch_bounds__(256) void deg_count(const int* __restrict__ dst,
                                                 int* __restrict__ deg, int E)
{
    int e = blockIdx.x * 256 + threadIdx.x;
    if (e < E) atomicAdd(&deg[dst[e]], 1);
}

__global__ __launch_bounds__(256) void scan_block(const int* __restrict__ deg,
                                                  int* __restrict__ offs,
                                                  int* __restrict__ bsum, int N)
{
    __shared__ int tmp[256];
    int t = threadIdx.x;
    int i = blockIdx.x * 256 + t;
    int val = (i < N) ? deg[i] : 0;
    tmp[t] = val;
    __syncthreads();
    #pragma unroll
    for (int o = 1; o < 256; o <<= 1) {
        int x = (t >= o) ? tmp[t - o] : 0;
        __syncthreads();
        tmp[t] += x;
        __syncthreads();
    }
    if (i < N) offs[i] = tmp[t] - val;
    if (t == 255) bsum[blockIdx.x] = tmp[255];
}

__global__ __launch_bounds__(256) void scan_top(int* __restrict__ bsum)
{
    __shared__ int tmp[256];
    int t = threadIdx.x;
    int val = bsum[t];
    tmp[t] = val;
    __syncthreads();
    #pragma unroll
    for (int o = 1; o < 256; o <<= 1) {
        int x = (t >= o) ? tmp[t - o] : 0;
        __syncthreads();
        tmp[t] += x;
        __syncthreads();
    }
    bsum[t] = tmp[t] - val;
}

__global__ __launch_bounds__(256) void scan_add(int* __restrict__ offs,
                                                const int* __restrict__ bsum, int N)
{
    int i = blockIdx.x * 256 + threadIdx.x;
    if (i < N) offs[i] += bsum[blockIdx.x];
}

__global__ __launch_bounds__(256) void scatter_k(
    const int* __restrict__ dst, const int* __restrict__ src,
    const float* __restrict__ pre_w,
    const int* __restrict__ offs, int* __restrict__ cursor,
    int* __restrict__ srcs, float* __restrict__ pws, int E)
{
    int e = blockIdx.x * 256 + threadIdx.x;
    if (e < E) {
        int d = dst[e];
        int p = atomicAdd(&cursor[d], 1);
        int pos = offs[d] + p;
        srcs[pos] = src[e];        // pre-gathered: main_k reads contiguous
        pws[pos]  = pre_w[e];
    }
}

// ---------------------------------------------------------------------------
// main_k: one wave per dst node, lane = output dim.
// Edge scalars (a, exp, pw*vr) computed lane-parallel; den/msum via shuffle
// reductions; only the per-dim gathers (proj_z, gp) run in the broadcast
// loop, 2-way unrolled for memory-level parallelism.
// ---------------------------------------------------------------------------
__global__ __launch_bounds__(256) void main_k(
    const float* __restrict__ proj_z,
    const float* __restrict__ sl, const float* __restrict__ sr,
    const float* __restrict__ vg0, const float* __restrict__ vr,
    const float* __restrict__ gp, const float* __restrict__ gm,
    const int* __restrict__ deg, const int* __restrict__ offs,
    const int* __restrict__ srcs, const float* __restrict__ pws,
    float* __restrict__ out, int N)
{
    int n = (blockIdx.x * blockDim.x + threadIdx.x) >> 6;
    int lane = threadIdx.x & 63;
    if (n >= N) return;

    int dg = deg[n];
    int st = offs[n];
    float srn = sr[n];

    float m = -INFINITY, den = 0.f, hacc = 0.f, mf = -INFINITY, msum = 0.f;

    for (int base = 0; base < dg; base += 64) {
        int cnt = min(64, dg - base);

        int s_e = 0; float pw = 0.f, lr = -INFINITY, vre = 0.f;
        if (lane < cnt) {
            s_e = srcs[st + base + lane];        // contiguous segment
            pw  = pws[st + base + lane];
            float a = fmaf(pw, sl[s_e], srn);
            lr = (a >= 0.f) ? a : NEG_SLOPE * a;
            vre = vr[s_e];
        }

        // chunk max + online rescale
        float cm = lr;
        #pragma unroll
        for (int o = 32; o > 0; o >>= 1) cm = fmaxf(cm, __shfl_xor(cm, o));
        if (cm > m) {
            float sc = __expf(m - cm);           // m=-inf -> 0: zeroes empty acc
            den *= sc; hacc *= sc; m = cm;
        }

        // lane-parallel exp + reductions for den and msum
        float ex  = (lane < cnt) ? __expf(lr - m) : 0.f;
        float rs1 = ex, rs2 = pw * vre;          // pw=0 on idle lanes
        #pragma unroll
        for (int o = 32; o > 0; o >>= 1) {
            rs1 += __shfl_xor(rs1, o);
            rs2 += __shfl_xor(rs2, o);
        }
        den += rs1; msum += rs2;

        // per-dim gathers, 2-way unrolled
        int j = 0;
        for (; j + 1 < cnt; j += 2) {
            int   s0 = __shfl(s_e, j),     s1 = __shfl(s_e, j + 1);
            float e0 = __shfl(ex, j),      e1 = __shfl(ex, j + 1);
            float q0 = __shfl(pw, j),      q1 = __shfl(pw, j + 1);
            size_t b0 = (size_t)s0 * 64 + lane;
            size_t b1 = (size_t)s1 * 64 + lane;
            float pz0 = proj_z[b0], g0 = gp[b0];
            float pz1 = proj_z[b1], g1 = gp[b1];
            hacc = fmaf(e0, pz0, hacc);
            mf   = fmaxf(mf, q0 * g0);
            hacc = fmaf(e1, pz1, hacc);
            mf   = fmaxf(mf, q1 * g1);
        }
        if (j < cnt) {
            int   s0 = __shfl(s_e, j);
            float e0 = __shfl(ex, j);
            float q0 = __shfl(pw, j);
            size_t b0 = (size_t)s0 * 64 + lane;
            hacc = fmaf(e0, proj_z[b0], hacc);
            mf   = fmaxf(mf, q0 * gp[b0]);
        }
    }

    // gate
    float mfv = (dg > 0) ? mf : 0.f;
    float gdot = gm[lane] * mfv;
    #pragma unroll
    for (int o = 32; o > 0; o >>= 1) gdot += __shfl_xor(gdot, o);
    float mean = msum / fmaxf((float)dg, 1.f);
    float x = vg0[n] + gdot + mean;
    float gv = 1.f / (1.f + __expf(-x));

    float pz = proj_z[(size_t)n * 64 + lane];
    out[(size_t)n * 64 + lane] = pz + ((dg > 0) ? gv * hacc / den : 0.f);
}

// ---------------------------------------------------------------------------
extern "C" void kernel_launch(void* const* d_in, const int* in_sizes, int n_in,
                              void* d_out, int out_size, void* d_ws, size_t ws_size,
                              hipStream_t stream)
{
    const float* v      = (const float*)d_in[0];
    const float* proj_z = (const float*)d_in[1];
    const float* pre_w  = (const float*)d_in[2];
    const float* Wa_w   = (const float*)d_in[3];
    const float* attl_w = (const float*)d_in[4];
    const float* attr_w = (const float*)d_in[5];
    const float* Wg_w   = (const float*)d_in[6];
    const float* gl_w   = (const float*)d_in[7];
    const float* gm_w   = (const float*)d_in[8];
    const float* gr_w   = (const float*)d_in[9];
    const int*   src    = (const int*)d_in[10];
    const int*   dst    = (const int*)d_in[11];

    const int N = in_sizes[0] / 64;
    const int E = in_sizes[10];
    float* out = (float*)d_out;

    // workspace carve-up (~26.5 MB for N=65536, E=1M)
    char* ws = (char*)d_ws;
    float* sl     = (float*)ws; ws += (size_t)N * 4;
    float* sr     = (float*)ws; ws += (size_t)N * 4;
    float* vg0    = (float*)ws; ws += (size_t)N * 4;
    float* vr     = (float*)ws; ws += (size_t)N * 4;
    float* gp     = (float*)ws; ws += (size_t)N * 64 * 4;
    int*   deg    = (int*)ws;   ws += (size_t)N * 4;
    int*   offs   = (int*)ws;   ws += (size_t)N * 4;
    int*   cursor = (int*)ws;   ws += (size_t)N * 4;
    int*   bsum   = (int*)ws;   ws += 256 * 4;
    int*   srcs   = (int*)ws;   ws += (size_t)E * 4;
    float* pws    = (float*)ws; ws += (size_t)E * 4;

    hipMemsetAsync(deg, 0, (size_t)N * 4, stream);
    hipMemsetAsync(cursor, 0, (size_t)N * 4, stream);

    int nTiles = (N + 63) / 64;
    int npb = nTiles < 1024 ? nTiles : 1024;
    node_pre<<<npb, 256, 0, stream>>>(v, Wa_w, attl_w, attr_w, Wg_w,
                                      gl_w, gr_w, sl, sr, vg0, vr, gp, N);
    deg_count<<<(E + 255) / 256, 256, 0, stream>>>(dst, deg, E);

    int nScanBlocks = (N + 255) / 256;   // 256 for N=65536
    scan_block<<<nScanBlocks, 256, 0, stream>>>(deg, offs, bsum, N);
    scan_top<<<1, 256, 0, stream>>>(bsum);
    scan_add<<<nScanBlocks, 256, 0, stream>>>(offs, bsum, N);

    scatter_k<<<(E + 255) / 256, 256, 0, stream>>>(dst, src, pre_w, offs, cursor,
                                                   srcs, pws, E);

    main_k<<<(N + 3) / 4, 256, 0, stream>>>(proj_z, sl, sr, vg0, vr,
                                            gp, gm_w, deg, offs, srcs, pws, out, N);
}

// Round 3
// 212.390 us; speedup vs baseline: 1.9964x; 1.1979x over previous
//
#include <hip/hip_runtime.h>
#include <hip/hip_bf16.h>
#include <math.h>

#define NEG_SLOPE 0.01f

__device__ __forceinline__ unsigned int pack2bf16(float pz, float g)
{
    __hip_bfloat16 a = __float2bfloat16(pz);   // RNE
    __hip_bfloat16 b = __float2bfloat16(g);
    unsigned short ua = *(unsigned short*)&a;
    unsigned short ub = *(unsigned short*)&b;
    return ((unsigned int)ub << 16) | ua;
}

// ---------------------------------------------------------------------------
// node_pre: per-node precompute + fused degree count.
//   sl[n]  = v[n] . (attl @ Wa)   sr[n] = v[n] . (attr @ Wa)
//   vg0[n] = v[n] . gl            vr[n] = v[n] . gr
//   pzgp[n][d] = pack(bf16(proj_z[n][d]), bf16((Wg @ v[n])[d]))
// One 64-node tile per block iteration; wave per 16 nodes, lane = dim.
// Wg rows in registers (lane d = row d); v tile in stride-68 LDS.
// ---------------------------------------------------------------------------
__global__ __launch_bounds__(256) void node_pre(
    const float* __restrict__ v, const float* __restrict__ proj_z,
    const float* __restrict__ Wa,
    const float* __restrict__ attl, const float* __restrict__ attr,
    const float* __restrict__ Wg, const float* __restrict__ gl,
    const float* __restrict__ gr, const int* __restrict__ dst,
    float* __restrict__ sl, float* __restrict__ sr,
    float* __restrict__ vg0, float* __restrict__ vr,
    unsigned int* __restrict__ pzgp, int* __restrict__ deg,
    int N, int E)
{
    // fused degree count (independent work, overlaps with tile compute below)
    for (int e = blockIdx.x * blockDim.x + threadIdx.x; e < E;
         e += gridDim.x * blockDim.x)
        atomicAdd(&deg[dst[e]], 1);

    __shared__ float vtile[64 * 68];   // stride 68: conflict-free
    int t = threadIdx.x;
    int lane = t & 63;
    int w = t >> 6;

    // lane d holds Wg row d
    float wcol[64];
    #pragma unroll
    for (int k4 = 0; k4 < 64; k4 += 4) {
        float4 q = *(const float4*)(Wg + lane * 64 + k4);
        wcol[k4] = q.x; wcol[k4 + 1] = q.y; wcol[k4 + 2] = q.z; wcol[k4 + 3] = q.w;
    }

    // al/ar once per wave: al[d] = sum_k attl[k]*Wa[k][d]
    float ald = 0.f, ard = 0.f;
    #pragma unroll 8
    for (int k = 0; k < 64; ++k) {
        float wa = Wa[k * 64 + lane];
        ald = fmaf(attl[k], wa, ald);
        ard = fmaf(attr[k], wa, ard);
    }
    float gld = gl[lane], grd = gr[lane];

    for (int tile = blockIdx.x; (size_t)tile * 64 < (size_t)N; tile += gridDim.x) {
        int base = tile * 64;
        __syncthreads();
        #pragma unroll
        for (int i = 0; i < 4; ++i) {
            int el = t * 16 + i * 4;
            size_t gidx = (size_t)base * 64 + el;
            if (gidx + 3 < (size_t)N * 64) {
                float4 q = *(const float4*)(v + gidx);
                int r = el >> 6, c = el & 63;
                *(float4*)&vtile[r * 68 + c] = q;
            }
        }
        __syncthreads();

        #pragma unroll 4
        for (int n = 0; n < 16; ++n) {
            int ln = w * 16 + n;
            int node = base + ln;
            if (node >= N) break;
            float vd = vtile[ln * 68 + lane];

            float p1 = ald * vd, p2 = ard * vd, p3 = gld * vd, p4 = grd * vd;
            #pragma unroll
            for (int o = 32; o > 0; o >>= 1) {
                p1 += __shfl_xor(p1, o);
                p2 += __shfl_xor(p2, o);
                p3 += __shfl_xor(p3, o);
                p4 += __shfl_xor(p4, o);
            }
            if (lane == 0) { sl[node] = p1; sr[node] = p2; vg0[node] = p3; vr[node] = p4; }

            float acc = 0.f;
            #pragma unroll
            for (int k = 0; k < 64; k += 4) {
                float4 q = *(const float4*)&vtile[ln * 68 + k];  // uniform addr
                acc = fmaf(wcol[k], q.x, acc);
                acc = fmaf(wcol[k + 1], q.y, acc);
                acc = fmaf(wcol[k + 2], q.z, acc);
                acc = fmaf(wcol[k + 3], q.w, acc);
            }
            float pz = proj_z[(size_t)node * 64 + lane];
            pzgp[(size_t)node * 64 + lane] = pack2bf16(pz, acc);
        }
    }
}

// ---------------------------------------------------------------------------
// scan_alloc: per-block exclusive scan of deg + atomic base allocation.
// Segments stay contiguous per node; cross-block ordering is arbitrary
// (only permutes fp summation order, within validation tolerance).
// ---------------------------------------------------------------------------
__global__ __launch_bounds__(256) void scan_alloc(const int* __restrict__ deg,
                                                  int* __restrict__ offs,
                                                  int* __restrict__ gcount, int N)
{
    __shared__ int tmp[256];
    __shared__ int base;
    int t = threadIdx.x;
    int i = blockIdx.x * 256 + t;
    int val = (i < N) ? deg[i] : 0;
    tmp[t] = val;
    __syncthreads();
    #pragma unroll
    for (int o = 1; o < 256; o <<= 1) {
        int x = (t >= o) ? tmp[t - o] : 0;
        __syncthreads();
        tmp[t] += x;
        __syncthreads();
    }
    if (t == 255) base = atomicAdd(gcount, tmp[255]);
    __syncthreads();
    if (i < N) offs[i] = base + tmp[t] - val;
}

// ---------------------------------------------------------------------------
// scatter_k: group (src, pre_w) by dst into contiguous segments, packed int2
// ---------------------------------------------------------------------------
__global__ __launch_bounds__(256) void scatter_k(
    const int* __restrict__ dst, const int* __restrict__ src,
    const float* __restrict__ pre_w,
    const int* __restrict__ offs, int* __restrict__ cursor,
    int2* __restrict__ edata, int E)
{
    int e = blockIdx.x * 256 + threadIdx.x;
    if (e < E) {
        int d = dst[e];
        int p = atomicAdd(&cursor[d], 1);
        int2 pk;
        pk.x = src[e];
        pk.y = __float_as_int(pre_w[e]);
        edata[offs[d] + p] = pk;
    }
}

// ---------------------------------------------------------------------------
// main_k: one wave per dst node, lane = output dim.
// Per-edge gather is ONE dword (packed bf16 pz|gp) per lane, 4-way unrolled.
// ---------------------------------------------------------------------------
__global__ __launch_bounds__(256) void main_k(
    const float* __restrict__ proj_z,
    const float* __restrict__ sl, const float* __restrict__ sr,
    const float* __restrict__ vg0, const float* __restrict__ vr,
    const unsigned int* __restrict__ pzgp, const float* __restrict__ gm,
    const int* __restrict__ deg, const int* __restrict__ offs,
    const int2* __restrict__ edata,
    float* __restrict__ out, int N)
{
    int n = (blockIdx.x * blockDim.x + threadIdx.x) >> 6;
    int lane = threadIdx.x & 63;
    if (n >= N) return;

    int dg = deg[n];
    int st = offs[n];
    float srn = sr[n];

    float m = -INFINITY, den = 0.f, hacc = 0.f, mf = -INFINITY, msum = 0.f;

    for (int base = 0; base < dg; base += 64) {
        int cnt = min(64, dg - base);

        int s_e = 0; float pw = 0.f, lr = -INFINITY, vre = 0.f;
        if (lane < cnt) {
            int2 ed = edata[st + base + lane];
            s_e = ed.x;
            pw  = __int_as_float(ed.y);
            float a = fmaf(pw, sl[s_e], srn);
            lr = (a >= 0.f) ? a : NEG_SLOPE * a;
            vre = vr[s_e];
        }

        // chunk max + online rescale
        float cm = lr;
        #pragma unroll
        for (int o = 32; o > 0; o >>= 1) cm = fmaxf(cm, __shfl_xor(cm, o));
        if (cm > m) {
            float sc = __expf(m - cm);
            den *= sc; hacc *= sc; m = cm;
        }

        // lane-parallel exp + reductions for den and msum
        float ex  = (lane < cnt) ? __expf(lr - m) : 0.f;
        float rs1 = ex, rs2 = pw * vre;
        #pragma unroll
        for (int o = 32; o > 0; o >>= 1) {
            rs1 += __shfl_xor(rs1, o);
            rs2 += __shfl_xor(rs2, o);
        }
        den += rs1; msum += rs2;

        // per-dim gathers: one dword per edge per lane, 4-way unrolled
        int j = 0;
        for (; j + 3 < cnt; j += 4) {
            int   s0 = __shfl(s_e, j),     s1 = __shfl(s_e, j + 1);
            int   s2 = __shfl(s_e, j + 2), s3 = __shfl(s_e, j + 3);
            float e0 = __shfl(ex, j),      e1 = __shfl(ex, j + 1);
            float e2 = __shfl(ex, j + 2),  e3 = __shfl(ex, j + 3);
            float q0 = __shfl(pw, j),      q1 = __shfl(pw, j + 1);
            float q2 = __shfl(pw, j + 2),  q3 = __shfl(pw, j + 3);
            unsigned int u0 = pzgp[(size_t)s0 * 64 + lane];
            unsigned int u1 = pzgp[(size_t)s1 * 64 + lane];
            unsigned int u2 = pzgp[(size_t)s2 * 64 + lane];
            unsigned int u3 = pzgp[(size_t)s3 * 64 + lane];
            hacc = fmaf(e0, __uint_as_float(u0 << 16), hacc);
            mf   = fmaxf(mf, q0 * __uint_as_float(u0 & 0xffff0000u));
            hacc = fmaf(e1, __uint_as_float(u1 << 16), hacc);
            mf   = fmaxf(mf, q1 * __uint_as_float(u1 & 0xffff0000u));
            hacc = fmaf(e2, __uint_as_float(u2 << 16), hacc);
            mf   = fmaxf(mf, q2 * __uint_as_float(u2 & 0xffff0000u));
            hacc = fmaf(e3, __uint_as_float(u3 << 16), hacc);
            mf   = fmaxf(mf, q3 * __uint_as_float(u3 & 0xffff0000u));
        }
        for (; j < cnt; ++j) {
            int   s0 = __shfl(s_e, j);
            float e0 = __shfl(ex, j);
            float q0 = __shfl(pw, j);
            unsigned int u0 = pzgp[(size_t)s0 * 64 + lane];
            hacc = fmaf(e0, __uint_as_float(u0 << 16), hacc);
            mf   = fmaxf(mf, q0 * __uint_as_float(u0 & 0xffff0000u));
        }
    }

    // gate
    float mfv = (dg > 0) ? mf : 0.f;
    float gdot = gm[lane] * mfv;
    #pragma unroll
    for (int o = 32; o > 0; o >>= 1) gdot += __shfl_xor(gdot, o);
    float mean = msum / fmaxf((float)dg, 1.f);
    float x = vg0[n] + gdot + mean;
    float gv = 1.f / (1.f + __expf(-x));

    float pz = proj_z[(size_t)n * 64 + lane];
    out[(size_t)n * 64 + lane] = pz + ((dg > 0) ? gv * hacc / den : 0.f);
}

// ---------------------------------------------------------------------------
extern "C" void kernel_launch(void* const* d_in, const int* in_sizes, int n_in,
                              void* d_out, int out_size, void* d_ws, size_t ws_size,
                              hipStream_t stream)
{
    const float* v      = (const float*)d_in[0];
    const float* proj_z = (const float*)d_in[1];
    const float* pre_w  = (const float*)d_in[2];
    const float* Wa_w   = (const float*)d_in[3];
    const float* attl_w = (const float*)d_in[4];
    const float* attr_w = (const float*)d_in[5];
    const float* Wg_w   = (const float*)d_in[6];
    const float* gl_w   = (const float*)d_in[7];
    const float* gm_w   = (const float*)d_in[8];
    const float* gr_w   = (const float*)d_in[9];
    const int*   src    = (const int*)d_in[10];
    const int*   dst    = (const int*)d_in[11];

    const int N = in_sizes[0] / 64;
    const int E = in_sizes[10];
    float* out = (float*)d_out;

    // workspace carve-up (~26 MB for N=65536, E=1M); edata 8B-aligned.
    char* ws = (char*)d_ws;
    unsigned int* pzgp = (unsigned int*)ws; ws += (size_t)N * 64 * 4;
    int2*  edata  = (int2*)ws;  ws += (size_t)E * 8;
    float* sl     = (float*)ws; ws += (size_t)N * 4;
    float* sr     = (float*)ws; ws += (size_t)N * 4;
    float* vg0    = (float*)ws; ws += (size_t)N * 4;
    float* vr     = (float*)ws; ws += (size_t)N * 4;
    int*   offs   = (int*)ws;   ws += (size_t)N * 4;
    int*   deg    = (int*)ws;   ws += (size_t)N * 4;   // zero zone start
    int*   cursor = (int*)ws;   ws += (size_t)N * 4;
    int*   gcount = (int*)ws;   ws += 4;

    // one memset covers deg + cursor + gcount (contiguous)
    hipMemsetAsync(deg, 0, ((size_t)2 * N + 1) * 4, stream);

    int nTiles = (N + 63) / 64;
    int npb = nTiles < 1024 ? nTiles : 1024;
    node_pre<<<npb, 256, 0, stream>>>(v, proj_z, Wa_w, attl_w, attr_w, Wg_w,
                                      gl_w, gr_w, dst, sl, sr, vg0, vr,
                                      pzgp, deg, N, E);

    scan_alloc<<<(N + 255) / 256, 256, 0, stream>>>(deg, offs, gcount, N);

    scatter_k<<<(E + 255) / 256, 256, 0, stream>>>(dst, src, pre_w, offs, cursor,
                                                   edata, E);

    main_k<<<(N + 3) / 4, 256, 0, stream>>>(proj_z, sl, sr, vg0, vr,
                                            pzgp, gm_w, deg, offs, edata, out, N);
}

// Round 4
// 211.591 us; speedup vs baseline: 2.0039x; 1.0038x over previous
//
#include <hip/hip_runtime.h>
#include <hip/hip_bf16.h>
#include <math.h>

#define NEG_SLOPE 0.01f

__device__ __forceinline__ unsigned int pack2bf16(float pz, float g)
{
    __hip_bfloat16 a = __float2bfloat16(pz);   // RNE
    __hip_bfloat16 b = __float2bfloat16(g);
    unsigned short ua = *(unsigned short*)&a;
    unsigned short ub = *(unsigned short*)&b;
    return ((unsigned int)ub << 16) | ua;
}

// ---------------------------------------------------------------------------
// node_pre: per-node precompute + fused degree count.
//   sl[n]  = v[n] . (attl @ Wa)   sr[n] = v[n] . (attr @ Wa)
//   vg0[n] = v[n] . gl            vr[n] = v[n] . gr
//   pzgp[n][d] = pack(bf16(proj_z[n][d]), bf16((Wg @ v[n])[d]))
// One 64-node tile per block; wave per 16 nodes, lane = dim.
// Wg rows in registers (lane d = row d) -- needs >64 VGPRs, so we declare
// __launch_bounds__(256,4) (VGPR budget 128) to prevent scratch spill.
// ---------------------------------------------------------------------------
__global__ __launch_bounds__(256, 4) void node_pre(
    const float* __restrict__ v, const float* __restrict__ proj_z,
    const float* __restrict__ Wa,
    const float* __restrict__ attl, const float* __restrict__ attr,
    const float* __restrict__ Wg, const float* __restrict__ gl,
    const float* __restrict__ gr, const int* __restrict__ dst,
    float* __restrict__ sl, float* __restrict__ sr,
    float* __restrict__ vg0, float* __restrict__ vr,
    unsigned int* __restrict__ pzgp, int* __restrict__ deg,
    int N, int E)
{
    // fused degree count (independent work)
    for (int e = blockIdx.x * blockDim.x + threadIdx.x; e < E;
         e += gridDim.x * blockDim.x)
        atomicAdd(&deg[dst[e]], 1);

    __shared__ float vtile[64 * 68];   // stride 68: conflict-free
    int t = threadIdx.x;
    int lane = t & 63;
    int w = t >> 6;

    // lane d holds Wg row d (64 VGPRs)
    float wcol[64];
    #pragma unroll
    for (int k4 = 0; k4 < 64; k4 += 4) {
        float4 q = *(const float4*)(Wg + lane * 64 + k4);
        wcol[k4] = q.x; wcol[k4 + 1] = q.y; wcol[k4 + 2] = q.z; wcol[k4 + 3] = q.w;
    }

    // al/ar once per wave: al[d] = sum_k attl[k]*Wa[k][d]
    float ald = 0.f, ard = 0.f;
    #pragma unroll 8
    for (int k = 0; k < 64; ++k) {
        float wa = Wa[k * 64 + lane];
        ald = fmaf(attl[k], wa, ald);
        ard = fmaf(attr[k], wa, ard);
    }
    float gld = gl[lane], grd = gr[lane];

    for (int tile = blockIdx.x; (size_t)tile * 64 < (size_t)N; tile += gridDim.x) {
        int base = tile * 64;
        __syncthreads();
        #pragma unroll
        for (int i = 0; i < 4; ++i) {
            int el = t * 16 + i * 4;
            size_t gidx = (size_t)base * 64 + el;
            if (gidx + 3 < (size_t)N * 64) {
                float4 q = *(const float4*)(v + gidx);
                int r = el >> 6, c = el & 63;
                *(float4*)&vtile[r * 68 + c] = q;
            }
        }
        __syncthreads();

        #pragma unroll 2
        for (int n = 0; n < 16; ++n) {
            int ln = w * 16 + n;
            int node = base + ln;
            if (node >= N) break;
            float vd = vtile[ln * 68 + lane];

            float p1 = ald * vd, p2 = ard * vd, p3 = gld * vd, p4 = grd * vd;
            #pragma unroll
            for (int o = 32; o > 0; o >>= 1) {
                p1 += __shfl_xor(p1, o);
                p2 += __shfl_xor(p2, o);
                p3 += __shfl_xor(p3, o);
                p4 += __shfl_xor(p4, o);
            }
            if (lane == 0) { sl[node] = p1; sr[node] = p2; vg0[node] = p3; vr[node] = p4; }

            float acc = 0.f;
            #pragma unroll
            for (int k = 0; k < 64; k += 4) {
                float4 q = *(const float4*)&vtile[ln * 68 + k];  // uniform addr
                acc = fmaf(wcol[k], q.x, acc);
                acc = fmaf(wcol[k + 1], q.y, acc);
                acc = fmaf(wcol[k + 2], q.z, acc);
                acc = fmaf(wcol[k + 3], q.w, acc);
            }
            float pz = proj_z[(size_t)node * 64 + lane];
            pzgp[(size_t)node * 64 + lane] = pack2bf16(pz, acc);
        }
    }
}

// ---------------------------------------------------------------------------
// scan_alloc: per-block exclusive scan of deg + atomic base allocation.
// ---------------------------------------------------------------------------
__global__ __launch_bounds__(256) void scan_alloc(const int* __restrict__ deg,
                                                  int* __restrict__ offs,
                                                  int* __restrict__ gcount, int N)
{
    __shared__ int tmp[256];
    __shared__ int base;
    int t = threadIdx.x;
    int i = blockIdx.x * 256 + t;
    int val = (i < N) ? deg[i] : 0;
    tmp[t] = val;
    __syncthreads();
    #pragma unroll
    for (int o = 1; o < 256; o <<= 1) {
        int x = (t >= o) ? tmp[t - o] : 0;
        __syncthreads();
        tmp[t] += x;
        __syncthreads();
    }
    if (t == 255) base = atomicAdd(gcount, tmp[255]);
    __syncthreads();
    if (i < N) offs[i] = base + tmp[t] - val;
}

// ---------------------------------------------------------------------------
// scatter_k: group (src, pre_w) by dst into contiguous segments, packed int2
// ---------------------------------------------------------------------------
__global__ __launch_bounds__(256) void scatter_k(
    const int* __restrict__ dst, const int* __restrict__ src,
    const float* __restrict__ pre_w,
    const int* __restrict__ offs, int* __restrict__ cursor,
    int2* __restrict__ edata, int E)
{
    int e = blockIdx.x * 256 + threadIdx.x;
    if (e < E) {
        int d = dst[e];
        int p = atomicAdd(&cursor[d], 1);
        int2 pk;
        pk.x = src[e];
        pk.y = __float_as_int(pre_w[e]);
        edata[offs[d] + p] = pk;
    }
}

// ---------------------------------------------------------------------------
// main_k: one wave per dst node, lane = output dim.
// Per-edge gather is ONE dword (packed bf16 pz|gp) per lane, 4-way unrolled.
// ---------------------------------------------------------------------------
__global__ __launch_bounds__(256) void main_k(
    const float* __restrict__ proj_z,
    const float* __restrict__ sl, const float* __restrict__ sr,
    const float* __restrict__ vg0, const float* __restrict__ vr,
    const unsigned int* __restrict__ pzgp, const float* __restrict__ gm,
    const int* __restrict__ deg, const int* __restrict__ offs,
    const int2* __restrict__ edata,
    float* __restrict__ out, int N)
{
    int n = (blockIdx.x * blockDim.x + threadIdx.x) >> 6;
    int lane = threadIdx.x & 63;
    if (n >= N) return;

    int dg = deg[n];
    int st = offs[n];
    float srn = sr[n];

    float m = -INFINITY, den = 0.f, hacc = 0.f, mf = -INFINITY, msum = 0.f;

    for (int base = 0; base < dg; base += 64) {
        int cnt = min(64, dg - base);

        int s_e = 0; float pw = 0.f, lr = -INFINITY, vre = 0.f;
        if (lane < cnt) {
            int2 ed = edata[st + base + lane];
            s_e = ed.x;
            pw  = __int_as_float(ed.y);
            float a = fmaf(pw, sl[s_e], srn);
            lr = (a >= 0.f) ? a : NEG_SLOPE * a;
            vre = vr[s_e];
        }

        // chunk max + online rescale
        float cm = lr;
        #pragma unroll
        for (int o = 32; o > 0; o >>= 1) cm = fmaxf(cm, __shfl_xor(cm, o));
        if (cm > m) {
            float sc = __expf(m - cm);
            den *= sc; hacc *= sc; m = cm;
        }

        // lane-parallel exp + reductions for den and msum
        float ex  = (lane < cnt) ? __expf(lr - m) : 0.f;
        float rs1 = ex, rs2 = pw * vre;
        #pragma unroll
        for (int o = 32; o > 0; o >>= 1) {
            rs1 += __shfl_xor(rs1, o);
            rs2 += __shfl_xor(rs2, o);
        }
        den += rs1; msum += rs2;

        // per-dim gathers: one dword per edge per lane, 4-way unrolled
        int j = 0;
        for (; j + 3 < cnt; j += 4) {
            int   s0 = __shfl(s_e, j),     s1 = __shfl(s_e, j + 1);
            int   s2 = __shfl(s_e, j + 2), s3 = __shfl(s_e, j + 3);
            float e0 = __shfl(ex, j),      e1 = __shfl(ex, j + 1);
            float e2 = __shfl(ex, j + 2),  e3 = __shfl(ex, j + 3);
            float q0 = __shfl(pw, j),      q1 = __shfl(pw, j + 1);
            float q2 = __shfl(pw, j + 2),  q3 = __shfl(pw, j + 3);
            unsigned int u0 = pzgp[(size_t)s0 * 64 + lane];
            unsigned int u1 = pzgp[(size_t)s1 * 64 + lane];
            unsigned int u2 = pzgp[(size_t)s2 * 64 + lane];
            unsigned int u3 = pzgp[(size_t)s3 * 64 + lane];
            hacc = fmaf(e0, __uint_as_float(u0 << 16), hacc);
            mf   = fmaxf(mf, q0 * __uint_as_float(u0 & 0xffff0000u));
            hacc = fmaf(e1, __uint_as_float(u1 << 16), hacc);
            mf   = fmaxf(mf, q1 * __uint_as_float(u1 & 0xffff0000u));
            hacc = fmaf(e2, __uint_as_float(u2 << 16), hacc);
            mf   = fmaxf(mf, q2 * __uint_as_float(u2 & 0xffff0000u));
            hacc = fmaf(e3, __uint_as_float(u3 << 16), hacc);
            mf   = fmaxf(mf, q3 * __uint_as_float(u3 & 0xffff0000u));
        }
        for (; j < cnt; ++j) {
            int   s0 = __shfl(s_e, j);
            float e0 = __shfl(ex, j);
            float q0 = __shfl(pw, j);
            unsigned int u0 = pzgp[(size_t)s0 * 64 + lane];
            hacc = fmaf(e0, __uint_as_float(u0 << 16), hacc);
            mf   = fmaxf(mf, q0 * __uint_as_float(u0 & 0xffff0000u));
        }
    }

    // gate
    float mfv = (dg > 0) ? mf : 0.f;
    float gdot = gm[lane] * mfv;
    #pragma unroll
    for (int o = 32; o > 0; o >>= 1) gdot += __shfl_xor(gdot, o);
    float mean = msum / fmaxf((float)dg, 1.f);
    float x = vg0[n] + gdot + mean;
    float gv = 1.f / (1.f + __expf(-x));

    float pz = proj_z[(size_t)n * 64 + lane];
    out[(size_t)n * 64 + lane] = pz + ((dg > 0) ? gv * hacc / den : 0.f);
}

// ---------------------------------------------------------------------------
extern "C" void kernel_launch(void* const* d_in, const int* in_sizes, int n_in,
                              void* d_out, int out_size, void* d_ws, size_t ws_size,
                              hipStream_t stream)
{
    const float* v      = (const float*)d_in[0];
    const float* proj_z = (const float*)d_in[1];
    const float* pre_w  = (const float*)d_in[2];
    const float* Wa_w   = (const float*)d_in[3];
    const float* attl_w = (const float*)d_in[4];
    const float* attr_w = (const float*)d_in[5];
    const float* Wg_w   = (const float*)d_in[6];
    const float* gl_w   = (const float*)d_in[7];
    const float* gm_w   = (const float*)d_in[8];
    const float* gr_w   = (const float*)d_in[9];
    const int*   src    = (const int*)d_in[10];
    const int*   dst    = (const int*)d_in[11];

    const int N = in_sizes[0] / 64;
    const int E = in_sizes[10];
    float* out = (float*)d_out;

    // workspace carve-up (~26 MB for N=65536, E=1M); edata 8B-aligned.
    char* ws = (char*)d_ws;
    unsigned int* pzgp = (unsigned int*)ws; ws += (size_t)N * 64 * 4;
    int2*  edata  = (int2*)ws;  ws += (size_t)E * 8;
    float* sl     = (float*)ws; ws += (size_t)N * 4;
    float* sr     = (float*)ws; ws += (size_t)N * 4;
    float* vg0    = (float*)ws; ws += (size_t)N * 4;
    float* vr     = (float*)ws; ws += (size_t)N * 4;
    int*   offs   = (int*)ws;   ws += (size_t)N * 4;
    int*   deg    = (int*)ws;   ws += (size_t)N * 4;   // zero zone start
    int*   cursor = (int*)ws;   ws += (size_t)N * 4;
    int*   gcount = (int*)ws;   ws += 4;

    // one memset covers deg + cursor + gcount (contiguous)
    hipMemsetAsync(deg, 0, ((size_t)2 * N + 1) * 4, stream);

    int nTiles = (N + 63) / 64;
    int npb = nTiles < 1024 ? nTiles : 1024;
    node_pre<<<npb, 256, 0, stream>>>(v, proj_z, Wa_w, attl_w, attr_w, Wg_w,
                                      gl_w, gr_w, dst, sl, sr, vg0, vr,
                                      pzgp, deg, N, E);

    scan_alloc<<<(N + 255) / 256, 256, 0, stream>>>(deg, offs, gcount, N);

    scatter_k<<<(E + 255) / 256, 256, 0, stream>>>(dst, src, pre_w, offs, cursor,
                                                   edata, E);

    main_k<<<(N + 3) / 4, 256, 0, stream>>>(proj_z, sl, sr, vg0, vr,
                                            pzgp, gm_w, deg, offs, edata, out, N);
}

// Round 5
// 201.315 us; speedup vs baseline: 2.1062x; 1.0510x over previous
//
#include <hip/hip_runtime.h>
#include <hip/hip_bf16.h>
#include <math.h>

#define NEG_SLOPE 0.01f

__device__ __forceinline__ unsigned int pack2bf16(float pz, float g)
{
    __hip_bfloat16 a = __float2bfloat16(pz);   // RNE
    __hip_bfloat16 b = __float2bfloat16(g);
    unsigned short ua = *(unsigned short*)&a;
    unsigned short ub = *(unsigned short*)&b;
    return ((unsigned int)ub << 16) | ua;
}

// ---------------------------------------------------------------------------
// node_pre: per-node precompute + fused degree count.
//   slvr[n] = (v[n].(attl@Wa), v[n].gr)      srvg[n] = (v[n].(attr@Wa), v[n].gl)
//   pzgp[n][d] = pack(bf16(proj_z[n][d]), bf16((Wg @ v[n])[d]))
// One 64-node tile per block; wave per 16 nodes, lane = dim.
// Register discipline: gp matmul is K-chunked (16 Wg floats + 16 accs live)
// so the kernel fits 64 VGPRs with NO scratch spill (round-4 lesson: the
// compiler spills rather than exceed its 64-VGPR occupancy target).
// Scalar dots are computed from staging registers + quad shfl-reduce.
// ---------------------------------------------------------------------------
__global__ __launch_bounds__(256) void node_pre(
    const float* __restrict__ v, const float* __restrict__ proj_z,
    const float* __restrict__ Wa,
    const float* __restrict__ attl, const float* __restrict__ attr,
    const float* __restrict__ Wg, const float* __restrict__ gl,
    const float* __restrict__ gr, const int* __restrict__ dst,
    float2* __restrict__ slvr, float2* __restrict__ srvg,
    unsigned int* __restrict__ pzgp, int* __restrict__ deg,
    int N, int E)
{
    // fused degree count (independent; overlaps with everything below)
    for (int e = blockIdx.x * blockDim.x + threadIdx.x; e < E;
         e += gridDim.x * blockDim.x)
        atomicAdd(&deg[dst[e]], 1);

    __shared__ float vtile[64 * 68];     // stride 68: conflict-free
    __shared__ float avecs[4][64];       // 0=al(=attl@Wa), 1=ar, 2=gl, 3=gr

    int t = threadIdx.x;
    int lane = t & 63;
    int w = t >> 6;

    // wave 0: build the 4 projection vectors in LDS
    if (w == 0) {
        float ald = 0.f, ard = 0.f;
        #pragma unroll 8
        for (int k = 0; k < 64; ++k) {
            float wa = Wa[k * 64 + lane];   // coalesced row read
            ald = fmaf(attl[k], wa, ald);
            ard = fmaf(attr[k], wa, ard);
        }
        avecs[0][lane] = ald;
        avecs[1][lane] = ard;
        avecs[2][lane] = gl[lane];
        avecs[3][lane] = gr[lane];
    }
    __syncthreads();

    for (int tile = blockIdx.x; (size_t)tile * 64 < (size_t)N; tile += gridDim.x) {
        int base = tile * 64;
        __syncthreads();                   // protect vtile/avecs from prev iter

        // stage 64x64 v tile; thread t owns node r=t>>2, cols (t&3)*16..+15.
        // Fuse the 4 scalar partial dot products on the in-register values.
        float p1 = 0.f, p2 = 0.f, p3 = 0.f, p4 = 0.f;
        #pragma unroll
        for (int i = 0; i < 4; ++i) {
            int el = t * 16 + i * 4;                   // 0..4095
            size_t gidx = (size_t)base * 64 + el;
            int c = (t & 3) * 16 + i * 4;              // col within row
            if (gidx + 3 < (size_t)N * 64) {
                float4 q = *(const float4*)(v + gidx);
                int r = el >> 6;
                *(float4*)&vtile[r * 68 + c] = q;
                float4 a0 = *(const float4*)&avecs[0][c];
                float4 a1 = *(const float4*)&avecs[1][c];
                float4 a2 = *(const float4*)&avecs[2][c];
                float4 a3 = *(const float4*)&avecs[3][c];
                p1 = fmaf(a0.x, q.x, fmaf(a0.y, q.y, fmaf(a0.z, q.z, fmaf(a0.w, q.w, p1))));
                p2 = fmaf(a1.x, q.x, fmaf(a1.y, q.y, fmaf(a1.z, q.z, fmaf(a1.w, q.w, p2))));
                p3 = fmaf(a2.x, q.x, fmaf(a2.y, q.y, fmaf(a2.z, q.z, fmaf(a2.w, q.w, p3))));
                p4 = fmaf(a3.x, q.x, fmaf(a3.y, q.y, fmaf(a3.z, q.z, fmaf(a3.w, q.w, p4))));
            }
        }
        __syncthreads();

        // quad-reduce (threads 4r..4r+3 share node r) and store scalars
        p1 += __shfl_xor(p1, 1); p1 += __shfl_xor(p1, 2);
        p2 += __shfl_xor(p2, 1); p2 += __shfl_xor(p2, 2);
        p3 += __shfl_xor(p3, 1); p3 += __shfl_xor(p3, 2);
        p4 += __shfl_xor(p4, 1); p4 += __shfl_xor(p4, 2);
        if ((t & 3) == 0) {
            int node = base + (t >> 2);
            if (node < N) {
                slvr[node] = make_float2(p1, p4);   // (sl, vr): per-edge gather pair
                srvg[node] = make_float2(p2, p3);   // (sr, vg0): per-node pair
            }
        }

        // gp = vtile @ Wg^T, K-chunked: only 16 Wg floats + 16 accs live.
        float accs[16];
        #pragma unroll
        for (int n = 0; n < 16; ++n) accs[n] = 0.f;

        #pragma unroll 1
        for (int kc = 0; kc < 4; ++kc) {
            const float* wrow = Wg + lane * 64 + kc * 16;
            float4 w0 = *(const float4*)(wrow + 0);
            float4 w1 = *(const float4*)(wrow + 4);
            float4 w2 = *(const float4*)(wrow + 8);
            float4 w3 = *(const float4*)(wrow + 12);
            #pragma unroll
            for (int n = 0; n < 16; ++n) {
                const float* vp = &vtile[(w * 16 + n) * 68 + kc * 16];  // uniform
                float4 q0 = *(const float4*)(vp + 0);
                float4 q1 = *(const float4*)(vp + 4);
                float4 q2 = *(const float4*)(vp + 8);
                float4 q3 = *(const float4*)(vp + 12);
                float a = accs[n];
                a = fmaf(w0.x, q0.x, a); a = fmaf(w0.y, q0.y, a);
                a = fmaf(w0.z, q0.z, a); a = fmaf(w0.w, q0.w, a);
                a = fmaf(w1.x, q1.x, a); a = fmaf(w1.y, q1.y, a);
                a = fmaf(w1.z, q1.z, a); a = fmaf(w1.w, q1.w, a);
                a = fmaf(w2.x, q2.x, a); a = fmaf(w2.y, q2.y, a);
                a = fmaf(w2.z, q2.z, a); a = fmaf(w2.w, q2.w, a);
                a = fmaf(w3.x, q3.x, a); a = fmaf(w3.y, q3.y, a);
                a = fmaf(w3.z, q3.z, a); a = fmaf(w3.w, q3.w, a);
                accs[n] = a;
            }
        }

        // pack (bf16 proj_z | bf16 gp) and store
        #pragma unroll
        for (int n = 0; n < 16; ++n) {
            int node = base + w * 16 + n;
            if (node < N) {
                float pz = proj_z[(size_t)node * 64 + lane];
                pzgp[(size_t)node * 64 + lane] = pack2bf16(pz, accs[n]);
            }
        }
    }
}

// ---------------------------------------------------------------------------
// scan_alloc: per-block exclusive scan of deg + atomic base allocation.
// ---------------------------------------------------------------------------
__global__ __launch_bounds__(256) void scan_alloc(const int* __restrict__ deg,
                                                  int* __restrict__ offs,
                                                  int* __restrict__ gcount, int N)
{
    __shared__ int tmp[256];
    __shared__ int base;
    int t = threadIdx.x;
    int i = blockIdx.x * 256 + t;
    int val = (i < N) ? deg[i] : 0;
    tmp[t] = val;
    __syncthreads();
    #pragma unroll
    for (int o = 1; o < 256; o <<= 1) {
        int x = (t >= o) ? tmp[t - o] : 0;
        __syncthreads();
        tmp[t] += x;
        __syncthreads();
    }
    if (t == 255) base = atomicAdd(gcount, tmp[255]);
    __syncthreads();
    if (i < N) offs[i] = base + tmp[t] - val;
}

// ---------------------------------------------------------------------------
// scatter_k: group (src, pre_w) by dst into contiguous segments, packed int2
// ---------------------------------------------------------------------------
__global__ __launch_bounds__(256) void scatter_k(
    const int* __restrict__ dst, const int* __restrict__ src,
    const float* __restrict__ pre_w,
    const int* __restrict__ offs, int* __restrict__ cursor,
    int2* __restrict__ edata, int E)
{
    int e = blockIdx.x * 256 + threadIdx.x;
    if (e < E) {
        int d = dst[e];
        int p = atomicAdd(&cursor[d], 1);
        int2 pk;
        pk.x = src[e];
        pk.y = __float_as_int(pre_w[e]);
        edata[offs[d] + p] = pk;
    }
}

// ---------------------------------------------------------------------------
// main_k: one wave per dst node, lane = output dim.
// Per-edge: 8B edata + 8B slvr (lane-parallel), then one dword pzgp gather
// per lane per edge (a coalesced 256B row read), 4-way unrolled.
// ---------------------------------------------------------------------------
__global__ __launch_bounds__(256) void main_k(
    const float* __restrict__ proj_z,
    const float2* __restrict__ slvr, const float2* __restrict__ srvg,
    const unsigned int* __restrict__ pzgp, const float* __restrict__ gm,
    const int* __restrict__ deg, const int* __restrict__ offs,
    const int2* __restrict__ edata,
    float* __restrict__ out, int N)
{
    int n = (blockIdx.x * blockDim.x + threadIdx.x) >> 6;
    int lane = threadIdx.x & 63;
    if (n >= N) return;

    int dg = deg[n];
    int st = offs[n];
    float2 sv = srvg[n];
    float srn = sv.x, vg0n = sv.y;

    float m = -INFINITY, den = 0.f, hacc = 0.f, mf = -INFINITY, msum = 0.f;

    for (int base = 0; base < dg; base += 64) {
        int cnt = min(64, dg - base);

        int s_e = 0; float pw = 0.f, lr = -INFINITY, vre = 0.f;
        if (lane < cnt) {
            int2 ed = edata[st + base + lane];
            s_e = ed.x;
            pw  = __int_as_float(ed.y);
            float2 f = slvr[s_e];
            float a = fmaf(pw, f.x, srn);
            lr = (a >= 0.f) ? a : NEG_SLOPE * a;
            vre = f.y;
        }

        // chunk max + online rescale
        float cm = lr;
        #pragma unroll
        for (int o = 32; o > 0; o >>= 1) cm = fmaxf(cm, __shfl_xor(cm, o));
        if (cm > m) {
            float sc = __expf(m - cm);
            den *= sc; hacc *= sc; m = cm;
        }

        // lane-parallel exp + reductions for den and msum
        float ex  = (lane < cnt) ? __expf(lr - m) : 0.f;
        float rs1 = ex, rs2 = pw * vre;
        #pragma unroll
        for (int o = 32; o > 0; o >>= 1) {
            rs1 += __shfl_xor(rs1, o);
            rs2 += __shfl_xor(rs2, o);
        }
        den += rs1; msum += rs2;

        // per-dim gathers: one dword per edge per lane, 4-way unrolled
        int j = 0;
        for (; j + 3 < cnt; j += 4) {
            int   s0 = __shfl(s_e, j),     s1 = __shfl(s_e, j + 1);
            int   s2 = __shfl(s_e, j + 2), s3 = __shfl(s_e, j + 3);
            float e0 = __shfl(ex, j),      e1 = __shfl(ex, j + 1);
            float e2 = __shfl(ex, j + 2),  e3 = __shfl(ex, j + 3);
            float q0 = __shfl(pw, j),      q1 = __shfl(pw, j + 1);
            float q2 = __shfl(pw, j + 2),  q3 = __shfl(pw, j + 3);
            unsigned int u0 = pzgp[(size_t)s0 * 64 + lane];
            unsigned int u1 = pzgp[(size_t)s1 * 64 + lane];
            unsigned int u2 = pzgp[(size_t)s2 * 64 + lane];
            unsigned int u3 = pzgp[(size_t)s3 * 64 + lane];
            hacc = fmaf(e0, __uint_as_float(u0 << 16), hacc);
            mf   = fmaxf(mf, q0 * __uint_as_float(u0 & 0xffff0000u));
            hacc = fmaf(e1, __uint_as_float(u1 << 16), hacc);
            mf   = fmaxf(mf, q1 * __uint_as_float(u1 & 0xffff0000u));
            hacc = fmaf(e2, __uint_as_float(u2 << 16), hacc);
            mf   = fmaxf(mf, q2 * __uint_as_float(u2 & 0xffff0000u));
            hacc = fmaf(e3, __uint_as_float(u3 << 16), hacc);
            mf   = fmaxf(mf, q3 * __uint_as_float(u3 & 0xffff0000u));
        }
        for (; j < cnt; ++j) {
            int   s0 = __shfl(s_e, j);
            float e0 = __shfl(ex, j);
            float q0 = __shfl(pw, j);
            unsigned int u0 = pzgp[(size_t)s0 * 64 + lane];
            hacc = fmaf(e0, __uint_as_float(u0 << 16), hacc);
            mf   = fmaxf(mf, q0 * __uint_as_float(u0 & 0xffff0000u));
        }
    }

    // gate
    float mfv = (dg > 0) ? mf : 0.f;
    float gdot = gm[lane] * mfv;
    #pragma unroll
    for (int o = 32; o > 0; o >>= 1) gdot += __shfl_xor(gdot, o);
    float mean = msum / fmaxf((float)dg, 1.f);
    float x = vg0n + gdot + mean;
    float gv = 1.f / (1.f + __expf(-x));

    float pz = proj_z[(size_t)n * 64 + lane];
    out[(size_t)n * 64 + lane] = pz + ((dg > 0) ? gv * hacc / den : 0.f);
}

// ---------------------------------------------------------------------------
extern "C" void kernel_launch(void* const* d_in, const int* in_sizes, int n_in,
                              void* d_out, int out_size, void* d_ws, size_t ws_size,
                              hipStream_t stream)
{
    const float* v      = (const float*)d_in[0];
    const float* proj_z = (const float*)d_in[1];
    const float* pre_w  = (const float*)d_in[2];
    const float* Wa_w   = (const float*)d_in[3];
    const float* attl_w = (const float*)d_in[4];
    const float* attr_w = (const float*)d_in[5];
    const float* Wg_w   = (const float*)d_in[6];
    const float* gl_w   = (const float*)d_in[7];
    const float* gm_w   = (const float*)d_in[8];
    const float* gr_w   = (const float*)d_in[9];
    const int*   src    = (const int*)d_in[10];
    const int*   dst    = (const int*)d_in[11];

    const int N = in_sizes[0] / 64;
    const int E = in_sizes[10];
    float* out = (float*)d_out;

    // workspace carve-up; edata/slvr/srvg 8B-aligned.
    char* ws = (char*)d_ws;
    unsigned int* pzgp = (unsigned int*)ws; ws += (size_t)N * 64 * 4;
    int2*   edata = (int2*)ws;   ws += (size_t)E * 8;
    float2* slvr  = (float2*)ws; ws += (size_t)N * 8;
    float2* srvg  = (float2*)ws; ws += (size_t)N * 8;
    int*    offs  = (int*)ws;    ws += (size_t)N * 4;
    int*    deg   = (int*)ws;    ws += (size_t)N * 4;   // zero zone start
    int*    cursor= (int*)ws;    ws += (size_t)N * 4;
    int*    gcount= (int*)ws;    ws += 4;

    // one memset covers deg + cursor + gcount (contiguous)
    hipMemsetAsync(deg, 0, ((size_t)2 * N + 1) * 4, stream);

    int nTiles = (N + 63) / 64;
    int npb = nTiles < 1024 ? nTiles : 1024;
    node_pre<<<npb, 256, 0, stream>>>(v, proj_z, Wa_w, attl_w, attr_w, Wg_w,
                                      gl_w, gr_w, dst, slvr, srvg,
                                      pzgp, deg, N, E);

    scan_alloc<<<(N + 255) / 256, 256, 0, stream>>>(deg, offs, gcount, N);

    scatter_k<<<(E + 255) / 256, 256, 0, stream>>>(dst, src, pre_w, offs, cursor,
                                                   edata, E);

    main_k<<<(N + 3) / 4, 256, 0, stream>>>(proj_z, slvr, srvg,
                                            pzgp, gm_w, deg, offs, edata, out, N);
}